// Round 1
// baseline (234.482 us; speedup 1.0000x reference)
//
#include <hip/hip_runtime.h>
#include <hip/hip_bf16.h>

typedef __bf16 bhalf;
typedef __attribute__((ext_vector_type(8))) __bf16 bhalf8;
typedef __attribute__((ext_vector_type(4))) __bf16 bhalf4;
typedef __attribute__((ext_vector_type(4))) float  f32x4;
typedef __attribute__((ext_vector_type(4))) short  s16x4;

#define NB   16
#define SEQ  2048
#define DIN  512
#define DOUT 64
#define NTOK (NB*SEQ)

// ws layout
#define WT_BYTES (192*512*2)              // 196608 B, 16B-aligned
#define Q_OFF    ((size_t)WT_BYTES)
#define QKV_BYTES ((size_t)NTOK*DOUT*2)   // 4 MiB each
#define K_OFF    (Q_OFF + QKV_BYTES)
#define VT_OFF   (K_OFF + QKV_BYTES)

// ---------------------------------------------------------------------------
// Kernel 0: W[0..2] fp32 [slot][k][col] -> Wt bf16 [n=slot*64+col][k]
// Fold (1/8)*log2(e) into slot 0 (Q) so attention scores are in exp2 units.
__global__ __launch_bounds__(256) void prep_w(const float* __restrict__ wk,
                                              bhalf* __restrict__ wt) {
  int tid  = blockIdx.x*256 + threadIdx.x;     // 0..98303
  int slot = tid >> 15;                        // /(512*64)
  int rem  = tid & 32767;
  int k    = rem >> 6;
  int col  = rem & 63;
  float v  = wk[tid];                          // coalesced read
  if (slot == 0) v *= 0.18033688011112042f;    // (1/8)*log2(e), folded scale
  wt[(size_t)(slot*64 + col)*DIN + k] = (bhalf)v;
}

// ---------------------------------------------------------------------------
// Kernel 1: QKV projection. 4 waves/block, wave = 16 token rows, N=192, K=512.
// C layout of mfma_f32_16x16x32_bf16: row=(lane>>4)*4+r, col=lane&15.
__global__ __launch_bounds__(256) void proj_qkv(const float* __restrict__ x,
    const bhalf* __restrict__ wt, bhalf* __restrict__ qb,
    bhalf* __restrict__ kb, bhalf* __restrict__ vtb) {
  __shared__ bhalf vlds[4][64][24];            // per-wave V transpose, pad=24 (16B-aligned rows)
  const int lane = threadIdx.x & 63;
  const int wv   = threadIdx.x >> 6;
  const int r16  = lane & 15;
  const int g    = lane >> 4;
  const int tokbase = blockIdx.x*64 + wv*16;

  f32x4 acc[12];
#pragma unroll
  for (int i = 0; i < 12; ++i) acc[i] = (f32x4){0.f, 0.f, 0.f, 0.f};

  const float* xrow = x  + (size_t)(tokbase + r16)*DIN + g*8;  // A: x[tok=r16][k]
  const bhalf* wrow = wt + (size_t)r16*DIN + g*8;              // B: Wt[n=r16+16nt][k]

  for (int kk = 0; kk < 16; ++kk) {
    f32x4 xa = *(const f32x4*)(xrow + kk*32);
    f32x4 xc = *(const f32x4*)(xrow + kk*32 + 4);
    bhalf8 a;
    a[0]=(bhalf)xa[0]; a[1]=(bhalf)xa[1]; a[2]=(bhalf)xa[2]; a[3]=(bhalf)xa[3];
    a[4]=(bhalf)xc[0]; a[5]=(bhalf)xc[1]; a[6]=(bhalf)xc[2]; a[7]=(bhalf)xc[3];
#pragma unroll
    for (int nt = 0; nt < 12; ++nt) {
      bhalf8 bfrag = *(const bhalf8*)(wrow + (size_t)nt*16*DIN + kk*32);
      acc[nt] = __builtin_amdgcn_mfma_f32_16x16x32_bf16(a, bfrag, acc[nt], 0, 0, 0);
    }
  }

  // Q (nt 0..3) and K (nt 4..7): store [tok][64] bf16
#pragma unroll
  for (int nt = 0; nt < 8; ++nt) {
    bhalf* dst = (nt < 4) ? qb : kb;
    int col = (nt & 3)*16 + r16;
#pragma unroll
    for (int rr = 0; rr < 4; ++rr) {
      int tok = tokbase + g*4 + rr;
      dst[(size_t)tok*DOUT + col] = (bhalf)acc[nt][rr];
    }
  }
  // V (nt 8..11): transpose via LDS -> V^T [b][64][2048]
#pragma unroll
  for (int nt = 8; nt < 12; ++nt) {
#pragma unroll
    for (int rr = 0; rr < 4; ++rr) {
      vlds[wv][(nt-8)*16 + r16][g*4 + rr] = (bhalf)acc[nt][rr];
    }
  }
  __syncthreads();
  {
    int f      = threadIdx.x & 63;                 // feature 0..63
    int tb     = blockIdx.x*64 + wv*16;            // this wave's tokens
    int b      = (blockIdx.x*64) >> 11;            // 2048 % 64 == 0: block within one batch
    int tokloc = tb & 2047;
    bhalf8 v0 = *(const bhalf8*)&vlds[wv][f][0];
    bhalf8 v1 = *(const bhalf8*)&vlds[wv][f][8];
    bhalf* dst = vtb + (size_t)b*(DOUT*SEQ) + (size_t)f*SEQ + tokloc;
    *(bhalf8*)dst       = v0;
    *(bhalf8*)(dst + 8) = v1;
  }
}

// ---------------------------------------------------------------------------
// Kernel 2: flash attention. 1 wave = 16 q rows; swapped QK^T so score regs
// are directly the A-fragment for PV's mfma_16x16x16bf16_1k. No LDS.
__global__ __launch_bounds__(256) void attn(const bhalf* __restrict__ qb,
    const bhalf* __restrict__ kb, const bhalf* __restrict__ vtb,
    float* __restrict__ out) {
  const int lane  = threadIdx.x & 63;
  const int wv    = threadIdx.x >> 6;
  const int r16   = lane & 15;
  const int g     = lane >> 4;
  const int qtile = blockIdx.x*4 + wv;     // 0..2047
  const int qbase = qtile*16;              // global token, 64-aligned per block
  const int b     = qbase >> 11;

  // Q fragments (B operand of S^T = mfma(K, Q)): Q[q=r16][k = kk*32 + g*8 + j]
  const bhalf* qrow = qb + (size_t)(qbase + r16)*DOUT + g*8;
  bhalf8 qf0 = *(const bhalf8*)(qrow);
  bhalf8 qf1 = *(const bhalf8*)(qrow + 32);

  const bhalf* kbat = kb  + (size_t)b*SEQ*DOUT;
  const bhalf* vbat = vtb + (size_t)b*DOUT*SEQ;

  f32x4 o0 = {0.f,0.f,0.f,0.f}, o1 = o0, o2 = o0, o3 = o0;
  float m = -INFINITY, lsum = 0.f;

  for (int kv = 0; kv < SEQ; kv += 16) {
    // K fragment (A operand): K[kv_row = r16][k]
    const bhalf* krow = kbat + (size_t)(kv + r16)*DOUT + g*8;
    bhalf8 kf0 = *(const bhalf8*)(krow);
    bhalf8 kf1 = *(const bhalf8*)(krow + 32);
    f32x4 s = {0.f,0.f,0.f,0.f};
    s = __builtin_amdgcn_mfma_f32_16x16x32_bf16(kf0, qf0, s, 0, 0, 0);
    s = __builtin_amdgcn_mfma_f32_16x16x32_bf16(kf1, qf1, s, 0, 0, 0);
    // s[r] = S^T[kv + g*4 + r][q = r16]  (already in exp2 units)

    float bm = fmaxf(fmaxf(s[0], s[1]), fmaxf(s[2], s[3]));
    bm = fmaxf(bm, __shfl_xor(bm, 16));
    bm = fmaxf(bm, __shfl_xor(bm, 32));     // all lanes: block max of row q=r16

    if (__any(bm > m)) {                    // wave-uniform; defer-rescale otherwise
      float mnew  = fmaxf(m, bm);
      float alpha = exp2f(m - mnew);        // lane's own q=r16
      m = mnew;
      lsum *= alpha;
      // redistribute alpha to O layout rows q = g*4+rr
      float a0 = __shfl(alpha, g*4 + 0, 16);
      float a1 = __shfl(alpha, g*4 + 1, 16);
      float a2 = __shfl(alpha, g*4 + 2, 16);
      float a3 = __shfl(alpha, g*4 + 3, 16);
      f32x4 av = {a0, a1, a2, a3};
      o0 *= av; o1 *= av; o2 *= av; o3 *= av;
    }

    f32x4 p;
    p[0] = exp2f(s[0] - m);
    p[1] = exp2f(s[1] - m);
    p[2] = exp2f(s[2] - m);
    p[3] = exp2f(s[3] - m);
    float ps = p[0] + p[1] + p[2] + p[3];
    ps += __shfl_xor(ps, 16);
    ps += __shfl_xor(ps, 32);
    lsum += ps;

    // P -> bf16; this IS the A-fragment of 16x16x16: A[q=r16][kv = g*4 + j]
    bhalf4 pv4;
    pv4[0] = (bhalf)p[0]; pv4[1] = (bhalf)p[1];
    pv4[2] = (bhalf)p[2]; pv4[3] = (bhalf)p[3];
    s16x4 pa = __builtin_bit_cast(s16x4, pv4);

    // V fragments (B operand): B[kv=g*4+j][d=dt*16+r16] = V^T[d][kv+g*4+j]
    const bhalf* vrow = vbat + (size_t)r16*SEQ + kv + g*4;
    s16x4 vf0 = __builtin_bit_cast(s16x4, *(const bhalf4*)(vrow));
    s16x4 vf1 = __builtin_bit_cast(s16x4, *(const bhalf4*)(vrow + 16*SEQ));
    s16x4 vf2 = __builtin_bit_cast(s16x4, *(const bhalf4*)(vrow + 32*SEQ));
    s16x4 vf3 = __builtin_bit_cast(s16x4, *(const bhalf4*)(vrow + 48*SEQ));

    o0 = __builtin_amdgcn_mfma_f32_16x16x16bf16_1k(pa, vf0, o0, 0, 0, 0);
    o1 = __builtin_amdgcn_mfma_f32_16x16x16bf16_1k(pa, vf1, o1, 0, 0, 0);
    o2 = __builtin_amdgcn_mfma_f32_16x16x16bf16_1k(pa, vf2, o2, 0, 0, 0);
    o3 = __builtin_amdgcn_mfma_f32_16x16x16bf16_1k(pa, vf3, o3, 0, 0, 0);
  }

  // epilogue: divide by row sums, write out[q][d] fp32
  float linv[4];
#pragma unroll
  for (int rr = 0; rr < 4; ++rr) {
    float L = __shfl(lsum, g*4 + rr, 16);
    linv[rr] = 1.0f / L;
  }
  float* obase = out + (size_t)qbase*DOUT;
#pragma unroll
  for (int rr = 0; rr < 4; ++rr) {
    obase[(g*4 + rr)*DOUT +  0 + r16] = o0[rr]*linv[rr];
    obase[(g*4 + rr)*DOUT + 16 + r16] = o1[rr]*linv[rr];
    obase[(g*4 + rr)*DOUT + 32 + r16] = o2[rr]*linv[rr];
    obase[(g*4 + rr)*DOUT + 48 + r16] = o3[rr]*linv[rr];
  }
}

// ---------------------------------------------------------------------------
extern "C" void kernel_launch(void* const* d_in, const int* in_sizes, int n_in,
                              void* d_out, int out_size, void* d_ws, size_t ws_size,
                              hipStream_t stream) {
  const float* x  = (const float*)d_in[0];   // [16,2048,512] fp32
  const float* wk = (const float*)d_in[1];   // [1000,512,64] fp32 (slots 0..2 used)
  float* out = (float*)d_out;                // [16,2048,64] fp32

  char* ws = (char*)d_ws;
  bhalf* wt = (bhalf*)(ws);
  bhalf* qq = (bhalf*)(ws + Q_OFF);
  bhalf* kk = (bhalf*)(ws + K_OFF);
  bhalf* vt = (bhalf*)(ws + VT_OFF);

  prep_w  <<<dim3(384), dim3(256), 0, stream>>>(wk, wt);
  proj_qkv<<<dim3(512), dim3(256), 0, stream>>>(x, wt, qq, kk, vt);
  attn    <<<dim3(512), dim3(256), 0, stream>>>(qq, kk, vt, out);
}